// Round 8
// baseline (1087.076 us; speedup 1.0000x reference)
//
#include <hip/hip_runtime.h>
#include <cmath>

#define NN 1024
#define BC 128
#define LS 24

typedef unsigned short u16;
typedef __attribute__((ext_vector_type(4))) float f32x4;
typedef __attribute__((ext_vector_type(8))) short bf16x8;

typedef __attribute__((address_space(1))) const void* as1cv;
typedef __attribute__((address_space(3))) void* as3v;

#define GLD16(gp, lp) __builtin_amdgcn_global_load_lds((as1cv)(gp), (as3v)(lp), 16, 0, 0)

__device__ __forceinline__ float sigf(float x){ return 1.0f/(1.0f+expf(-x)); }

__device__ __forceinline__ u16 f2b(float x){
  union { float f; unsigned u; } v; v.f = x;
  unsigned r = v.u + 0x7FFFu + ((v.u >> 16) & 1u);
  return (u16)(r >> 16);
}
__device__ __forceinline__ float b2f(u16 b){
  union { unsigned u; float f; } v; v.u = ((unsigned)b) << 16;
  return v.f;
}

// ---------------- fused preprocessing (independent parts) ----------------
// blocks [0,512): transpose; [512,576): colsum1; [576,592): packbias; [592,...): pack
__global__ void k_prep(const float* __restrict__ inputs, const float* __restrict__ adj,
                       const float* __restrict__ Wf, const float* __restrict__ Wi,
                       const float* __restrict__ Wo, const float* __restrict__ Wc,
                       const float* __restrict__ rWf, const float* __restrict__ rWi,
                       const float* __restrict__ rWo, const float* __restrict__ rWc,
                       const float* __restrict__ bf_, const float* __restrict__ bi_,
                       const float* __restrict__ bo_, const float* __restrict__ bc_,
                       const float* __restrict__ rbf, const float* __restrict__ rbi,
                       const float* __restrict__ rbo, const float* __restrict__ rbc,
                       u16* __restrict__ Xb, float* __restrict__ csum,
                       u16* __restrict__ Wgxb, u16* __restrict__ WgHp,
                       u16* __restrict__ rWgxb, u16* __restrict__ rWgHp,
                       float* __restrict__ bgcat){
  int b = blockIdx.x, tid = threadIdx.x;
  if (b < 512){
    int idx = b*256 + tid;                       // BC*NN
    const float4* p = (const float4*)(inputs + (size_t)idx*LS);
    float v[LS];
    #pragma unroll
    for (int q = 0; q < 6; ++q){
      float4 f = p[q];
      v[q*4]=f.x; v[q*4+1]=f.y; v[q*4+2]=f.z; v[q*4+3]=f.w;
    }
    #pragma unroll
    for (int t = 0; t < LS; ++t)
      Xb[(size_t)t*BC*NN + idx] = f2b(v[t]);
  } else if (b < 576){
    int bb = b - 512;
    for (int j = tid; j < 1024; j += 256){
      float s = 0.f;
      for (int i = 0; i < 16; ++i) s += adj[(size_t)(bb*16+i)*1024 + j];
      csum[(size_t)bb*1024 + j] = s;
    }
  } else if (b < 592){
    int idx = (b-576)*256 + tid;                 // 4096
    int seg = idx >> 10, j = idx & 1023;
    bgcat[idx]      = (seg==0?bf_: seg==1?bi_: seg==2?bo_:bc_)[j];
    bgcat[4096+idx] = (seg==0?rbf: seg==1?rbi: seg==2?rbo:rbc)[j];
  } else {
    int idx = (b-592)*256 + tid;
    if (idx < 16777216){
      int k = idx & 4095, r = idx >> 12, seg = r >> 10, j = r & 1023;
      const float* W = seg==0?Wf: seg==1?Wi: seg==2?Wo:Wc;
      float v = W[(size_t)j*4096 + k];
      if (k < 3072) Wgxb[(size_t)r*3072 + k] = f2b(v);
      else {
        int p = (j>>3)*32 + seg*8 + (j&7);
        WgHp[(size_t)p*1024 + (k-3072)] = f2b(v);
      }
    } else {
      int i2 = idx - 16777216;
      int k = i2 & 2047, r = i2 >> 11, seg = r >> 10, j = r & 1023;
      const float* W = seg==0?rWf: seg==1?rWi: seg==2?rWo:rWc;
      float v = W[(size_t)j*2048 + k];
      if (k < 1024) rWgxb[(size_t)r*1024 + k] = f2b(v);
      else {
        int p = (j>>3)*32 + seg*8 + (j&7);
        rWgHp[(size_t)p*1024 + (k-1024)] = f2b(v);
      }
    }
  }
}

__global__ void k_colsum2(const float* __restrict__ part, float* __restrict__ tmp){
  int j = blockIdx.x*256 + threadIdx.x;
  float s = 0.f;
  for (int b = 0; b < 64; ++b) s += part[(size_t)b*1024 + j];
  tmp[j] = (s == 0.f) ? 1e-5f : s;
}

// fused: A1b = bf16(min(tmp[i]*adj,1)); anormT = bf16(tmp[i]*adj)^T
__global__ void k_anormT(const float* __restrict__ adj, const float* __restrict__ tmp,
                         u16* __restrict__ A1b, u16* __restrict__ anormT){
  __shared__ u16 t[64][65];
  int bi = blockIdx.y*64, bj = blockIdx.x*64;
  for (int e = threadIdx.x; e < 4096; e += 256){
    int r = e >> 6, cc = e & 63;
    float v = tmp[bi+r]*adj[(size_t)(bi+r)*1024 + bj+cc];
    A1b[(size_t)(bi+r)*1024 + bj+cc] = f2b(fminf(v, 1.f));
    t[r][cc] = f2b(v);
  }
  __syncthreads();
  for (int e = threadIdx.x; e < 4096; e += 256){
    int r = e >> 6, cc = e & 63;
    anormT[(size_t)(bj+r)*1024 + bi+cc] = t[cc][r];
  }
}

__global__ void k_nbr(const u16* __restrict__ A3b, const float* __restrict__ nw,
                      float* __restrict__ nbr){
  __shared__ float red[256];
  int row = blockIdx.x;
  float s = 0.f;
  for (int j = threadIdx.x; j < 1024; j += 256)
    s += b2f(A3b[(size_t)row*1024 + j])*nw[j];
  red[threadIdx.x] = s; __syncthreads();
  for (int st = 128; st > 0; st >>= 1){
    if (threadIdx.x < st) red[threadIdx.x] += red[threadIdx.x+st];
    __syncthreads();
  }
  if (threadIdx.x == 0) nbr[row] = red[0];
}

__global__ void k_effT(const u16* __restrict__ Ap, const float* __restrict__ gcw,
                       u16* __restrict__ effb, u16* __restrict__ effbT){
  __shared__ u16 t[64][65];
  int bi = blockIdx.y*64, bj = blockIdx.x*64;   // bi over 3072, bj over 1024
  for (int e = threadIdx.x; e < 4096; e += 256){
    int r = e >> 6, cc = e & 63;
    size_t idx = (size_t)(bi+r)*1024 + bj+cc;
    u16 v = f2b(b2f(Ap[idx]) * gcw[idx]);
    effb[idx] = v;
    t[r][cc] = v;
  }
  __syncthreads();
  for (int e = threadIdx.x; e < 4096; e += 256){
    int r = e >> 6, cc = e & 63;
    effbT[(size_t)(bj+r)*3072 + bi+cc] = t[cc][r];
  }
}

// ---------------- bf16 MFMA NT GEMM, 128x128 tile (m97 structure) ----------------
__device__ __forceinline__ void mfma_tile(
    const u16* __restrict__ A, const u16* __restrict__ Bw, int K,
    const float* __restrict__ bias,
    float* __restrict__ outf, u16* __restrict__ outb, int ldc,
    u16* ldsA, u16* ldsB)
{
  const int tid  = threadIdx.x;
  const int lane = tid & 63;
  const int w    = tid >> 6;
  const int wr   = (w >> 1) * 64;
  const int wc   = (w & 1) * 64;
  f32x4 acc[4][4] = {};

  const int lrow = lane >> 3;
  const int srck = ((lane & 7) ^ lrow) * 8;
  for (int k0 = 0; k0 < K; k0 += 64){
    #pragma unroll
    for (int c = 0; c < 4; ++c){
      int row = w*32 + c*8;
      GLD16(A  + (size_t)(row + lrow)*K + k0 + srck, &ldsA[row*64]);
      GLD16(Bw + (size_t)(row + lrow)*K + k0 + srck, &ldsB[row*64]);
    }
    __syncthreads();
    #pragma unroll
    for (int kk = 0; kk < 2; ++kk) {
      bf16x8 af[4], bfr[4];
      #pragma unroll
      for (int mi = 0; mi < 4; ++mi) {
        int row = wr + mi*16 + (lane & 15);
        int grp = (kk*4 + (lane >> 4)) ^ (row & 7);
        af[mi] = *(const bf16x8*)&ldsA[row*64 + grp*8];
      }
      #pragma unroll
      for (int ni = 0; ni < 4; ++ni) {
        int row = wc + ni*16 + (lane & 15);
        int grp = (kk*4 + (lane >> 4)) ^ (row & 7);
        bfr[ni] = *(const bf16x8*)&ldsB[row*64 + grp*8];
      }
      #pragma unroll
      for (int mi = 0; mi < 4; ++mi)
        #pragma unroll
        for (int ni = 0; ni < 4; ++ni)
          acc[mi][ni] = __builtin_amdgcn_mfma_f32_16x16x32_bf16(af[mi], bfr[ni], acc[mi][ni], 0, 0, 0);
    }
    __syncthreads();
  }
  #pragma unroll
  for (int mi = 0; mi < 4; ++mi) {
    #pragma unroll
    for (int ni = 0; ni < 4; ++ni) {
      int col = wc + ni*16 + (lane & 15);
      #pragma unroll
      for (int q = 0; q < 4; ++q) {
        int row = wr + mi*16 + (lane >> 4)*4 + q;
        float v = acc[mi][ni][q];
        if (bias) v += bias[col];
        if (outf) outf[(size_t)row*ldc + col] = v;
        if (outb) outb[(size_t)row*ldc + col] = f2b(v);
      }
    }
  }
}

__global__ __launch_bounds__(256) void k_mfma_nt(
    const u16* __restrict__ A, const u16* __restrict__ B, int K,
    const float* __restrict__ bias, float* __restrict__ outf,
    u16* __restrict__ outb, int ldc)
{
  __shared__ u16 lds[16384];
  size_t i0 = (size_t)blockIdx.y * 128, j0 = (size_t)blockIdx.x * 128;
  mfma_tile(A + i0*K, B + j0*K, K,
            bias ? bias + j0 : nullptr,
            outf ? outf + i0*ldc + j0 : nullptr,
            outb ? outb + i0*ldc + j0 : nullptr, ldc,
            lds, lds + 8192);
}

// ---------------- 64x64-tile NT GEMM, BK=128 (32 KB LDS) ----------------
__global__ __launch_bounds__(256) void k_mfma64(
    const u16* __restrict__ Ag, const u16* __restrict__ Bg, int K,
    int clamp1, u16* __restrict__ outb, int ldc)
{
  __shared__ u16 ldsA[64*128];   // 16 KB
  __shared__ u16 ldsB[64*128];   // 16 KB
  const int tid  = threadIdx.x;
  const int lane = tid & 63;
  const int w    = tid >> 6;
  const int wr   = (w >> 1) * 32;
  const int wc   = (w & 1) * 32;
  const u16* A = Ag + (size_t)blockIdx.y*64*K;
  const u16* B = Bg + (size_t)blockIdx.x*64*K;
  f32x4 acc[2][2] = {};

  const int r4  = lane >> 4;           // 0..3 row offset within issue
  const int g16 = lane & 15;           // 16B group within row
  for (int k0 = 0; k0 < K; k0 += 128){
    #pragma unroll
    for (int c = 0; c < 4; ++c){
      int rowb = w*16 + c*4;
      int row = rowb + r4;
      int srcg = (g16 & 8) | ((g16 & 7) ^ (row & 7));
      GLD16(A + (size_t)row*K + k0 + srcg*8, &ldsA[rowb*128]);
      GLD16(B + (size_t)row*K + k0 + srcg*8, &ldsB[rowb*128]);
    }
    __syncthreads();
    #pragma unroll
    for (int kk = 0; kk < 4; ++kk){
      int idx = kk*4 + (lane >> 4);
      bf16x8 af[2], bfr[2];
      #pragma unroll
      for (int mi = 0; mi < 2; ++mi){
        int row = wr + mi*16 + (lane & 15);
        int pa = (idx & 8) | ((idx & 7) ^ (row & 7));
        af[mi] = *(const bf16x8*)&ldsA[row*128 + pa*8];
      }
      #pragma unroll
      for (int ni = 0; ni < 2; ++ni){
        int row = wc + ni*16 + (lane & 15);
        int pb = (idx & 8) | ((idx & 7) ^ (row & 7));
        bfr[ni] = *(const bf16x8*)&ldsB[row*128 + pb*8];
      }
      #pragma unroll
      for (int mi = 0; mi < 2; ++mi)
        #pragma unroll
        for (int ni = 0; ni < 2; ++ni)
          acc[mi][ni] = __builtin_amdgcn_mfma_f32_16x16x32_bf16(af[mi], bfr[ni], acc[mi][ni], 0, 0, 0);
    }
    __syncthreads();
  }
  #pragma unroll
  for (int mi = 0; mi < 2; ++mi){
    #pragma unroll
    for (int ni = 0; ni < 2; ++ni){
      int col = blockIdx.x*64 + wc + ni*16 + (lane & 15);
      #pragma unroll
      for (int q = 0; q < 4; ++q){
        int row = blockIdx.y*64 + wr + mi*16 + (lane >> 4)*4 + q;
        float v = acc[mi][ni][q];
        if (clamp1) v = fminf(v, 1.f);
        outb[(size_t)row*ldc + col] = f2b(v);
      }
    }
  }
}

// ---------------- fused per-step kernel: LSTM (512 blocks) + next-pre tiles (64 blocks) ----
// LSTM: job = bid>>8; rem = bid&255; s = rem>>1 (8 gate cells x 4 segs = 32 packed cols);
//       r0 = (rem&1)*64. GEMM M=64, N=32, K=1024, BK=256.
// Pre:  bid in [512,576): 128x128 tile of pre-slice t+1 = X_{t+1} @ Bcat^T + bgcat.
__global__ __launch_bounds__(256) void k_step(
    const u16* __restrict__ WgHp, const u16* __restrict__ rWgHp,
    const u16* __restrict__ pre_t,           // [BC][8192] bf16; job*4096 col offset
    const u16* __restrict__ Xb_next, const u16* __restrict__ Bcat,
    const float* __restrict__ bgcat, u16* __restrict__ pre_next, int do_pre,
    const float* __restrict__ nbrv,
    u16* __restrict__ Hb2, u16* __restrict__ rHb2,
    float* __restrict__ Cs, float* __restrict__ rCs,
    float* __restrict__ Hf, float* __restrict__ rHf,
    int ph, int last)
{
  __shared__ u16 lds[24576];   // 48 KB shared by both paths

  const int tid  = threadIdx.x;
  const int lane = tid & 63;
  const int w    = tid >> 6;          // 0..3
  const int bid  = blockIdx.x;

  if (bid >= 512){
    if (!do_pre) return;
    size_t j0 = (size_t)(bid - 512) * 128;
    mfma_tile(Xb_next, Bcat + j0*1024, 1024, bgcat + j0,
              nullptr, pre_next + j0, 8192, lds, lds + 8192);
    return;
  }

  const int job  = bid >> 8;
  const int rem  = bid & 255;
  const int s    = rem >> 1;
  const int r0   = (rem & 1) * 64;

  const u16* Bp   = (job ? rWgHp : WgHp) + (size_t)s*32*1024;
  const u16* Ab   = (job ? rHb2 : Hb2) + (size_t)ph*BC*NN + (size_t)r0*NN;
  const u16* pret = pre_t + (size_t)job*4096;
  u16* Hnext  = (job ? rHb2 : Hb2) + (size_t)(ph^1)*BC*NN;
  float* Csb  = job ? rCs : Cs;
  float* Hfin = job ? rHf : Hf;

  u16* ldsA = lds;            // 64*256
  u16* ldsB = lds + 16384;    // 32*256

  const int g32   = lane & 31;       // 16B group within 512B row
  const int rhalf = lane >> 5;       // 0..1 row offset within issue

  f32x4 acc[2] = {};
  for (int t = 0; t < 4; ++t){
    int k0 = t*256;
    #pragma unroll
    for (int c = 0; c < 8; ++c){
      int rowb = w*16 + c*2;
      int row = rowb + rhalf;
      int srcg = (g32 & 24) | ((g32 & 7) ^ (row & 7));
      GLD16(Ab + (size_t)row*1024 + k0 + srcg*8, &ldsA[rowb*256]);
    }
    #pragma unroll
    for (int c = 0; c < 4; ++c){
      int rowb = w*8 + c*2;
      int row = rowb + rhalf;
      int srcg = (g32 & 24) | ((g32 & 7) ^ (row & 7));
      GLD16(Bp + (size_t)row*1024 + k0 + srcg*8, &ldsB[rowb*256]);
    }
    __syncthreads();
    #pragma unroll
    for (int kk = 0; kk < 8; ++kk){
      int idx = kk*4 + (lane >> 4);
      int rowa = w*16 + (lane & 15);
      int pa = (idx & 24) | ((idx & 7) ^ (rowa & 7));
      bf16x8 af = *(const bf16x8*)&ldsA[rowa*256 + pa*8];
      #pragma unroll
      for (int ni = 0; ni < 2; ++ni){
        int rowb2 = ni*16 + (lane & 15);
        int pb = (idx & 24) | ((idx & 7) ^ (rowb2 & 7));
        bf16x8 bv = *(const bf16x8*)&ldsB[rowb2*256 + pb*8];
        acc[ni] = __builtin_amdgcn_mfma_f32_16x16x32_bf16(af, bv, acc[ni], 0, 0, 0);
      }
    }
    __syncthreads();
  }

  // epilogue: + pre, gates via shfl_xor(8) (round-4 verified mapping)
  #pragma unroll
  for (int ni = 0; ni < 2; ++ni){
    int pcol = ni*16 + (lane & 15);
    int gcol = (pcol >> 3)*1024 + s*8 + (pcol & 7);
    #pragma unroll
    for (int q = 0; q < 4; ++q){
      int row = r0 + w*16 + (lane >> 4)*4 + q;
      acc[ni][q] += b2f(pret[(size_t)row*8192 + gcol]);
    }
  }
  const bool act = (lane & 15) < 8;
  const int  c   = lane & 7;
  const int  col = s*8 + c;
  float fac = 1.f;
  if (!job && act) fac = nbrv[col];
  #pragma unroll
  for (int q = 0; q < 4; ++q){
    float a0 = acc[0][q], a1 = acc[1][q];
    float p1 = __shfl_xor(a0, 8);   // seg1 (i-gate)
    float p3 = __shfl_xor(a1, 8);   // seg3 (Ct)
    if (act){
      int row = r0 + w*16 + (lane >> 4)*4 + q;
      float fg = sigf(a0), ig = sigf(p1), og = sigf(a1), ct = tanhf(p3);
      size_t cidx = (size_t)row*NN + col;
      float cs = fg*Csb[cidx]*fac + ig*ct;
      Csb[cidx] = cs;
      float h = og*tanhf(cs);
      Hnext[cidx] = f2b(h);
      if (last) Hfin[cidx] = h;
    }
  }
}

// ---------------- last-step statistics ----------------
__global__ void k_var1(const u16* __restrict__ Xl, const u16* __restrict__ gcl,
                       float* __restrict__ part){
  int ch = blockIdx.x & 1, seg = blockIdx.x >> 1;   // 64 blocks
  int tid = threadIdx.x;
  float s1=0.f,q1=0.f,s2=0.f,q2=0.f;
  for (int bb = 0; bb < 2; ++bb){
    int row = (seg*2+bb)*2 + ch;
    const u16* xr = Xl + (size_t)row*1024;
    for (int n = tid; n < 1024; n += 256){ float v = b2f(xr[n]); s1 += v; q1 += v*v; }
    const u16* gr = gcl + (size_t)row*3072;
    for (int n = tid; n < 3072; n += 256){ float v = b2f(gr[n]); s2 += v; q2 += v*v; }
  }
  __shared__ float red[256][4];
  red[tid][0]=s1; red[tid][1]=q1; red[tid][2]=s2; red[tid][3]=q2;
  __syncthreads();
  for (int st = 128; st > 0; st >>= 1){
    if (tid < st){ for (int z = 0; z < 4; ++z) red[tid][z] += red[tid+st][z]; }
    __syncthreads();
  }
  if (tid == 0){ for (int z = 0; z < 4; ++z) part[(size_t)blockIdx.x*4 + z] = red[0][z]; }
}

// fused var2 + pred + conv: one thread per (b,n), 256 blocks
__global__ void k_out(const float* __restrict__ H, const float* __restrict__ rH,
                      const float* __restrict__ part, const float* __restrict__ cptr,
                      const float* __restrict__ cw, const float* __restrict__ cb,
                      float* __restrict__ out){
  __shared__ float vsh[4];
  int tid = threadIdx.x;
  if (tid < 4){
    int ch = tid & 1, which = tid >> 1;   // which: 0=var1, 1=var2
    float s = 0.f, q = 0.f;
    for (int seg = 0; seg < 32; ++seg){
      const float* p = part + (size_t)(seg*2+ch)*4 + which*2;
      s += p[0]; q += p[1];
    }
    float n = which ? 196608.f : 65536.f;
    vsh[tid] = (q - s*s/n) / (n - 1.f);
  }
  __syncthreads();
  int idx = blockIdx.x*256 + tid;   // 64*1024
  int n = idx & 1023, b = idx >> 10;
  float c0 = cptr[0];
  float v10 = vsh[0], v11 = vsh[1], v20 = vsh[2], v21 = vsh[3];
  size_t i0 = (size_t)(b*2+0)*1024 + n, i1 = (size_t)(b*2+1)*1024 + n;
  float p0 = (H[i0]*v10*c0 + rH[i0]*v20) / (v10 + v20*c0);
  float p1 = (H[i1]*v11*c0 + rH[i1]*v21) / (v11 + v21*c0);
  float* ob = out + (size_t)b*24*1024 + n;
  #pragma unroll
  for (int o = 0; o < 24; ++o)
    ob[(size_t)o*1024] = p0*cw[o*2+0] + p1*cw[o*2+1] + cb[o];
}

// ---------------- launch ----------------
extern "C" void kernel_launch(void* const* d_in, const int* in_sizes, int n_in,
                              void* d_out, int out_size, void* d_ws, size_t ws_size,
                              hipStream_t stream) {
  const float* inputs = (const float*)d_in[0];
  const float* adj    = (const float*)d_in[1];
  const float* gcw    = (const float*)d_in[2];
  const float* Wf  = (const float*)d_in[3];  const float* bf_ = (const float*)d_in[4];
  const float* Wi  = (const float*)d_in[5];  const float* bi_ = (const float*)d_in[6];
  const float* Wo  = (const float*)d_in[7];  const float* bo_ = (const float*)d_in[8];
  const float* Wc  = (const float*)d_in[9];  const float* bc_ = (const float*)d_in[10];
  const float* rWf = (const float*)d_in[11]; const float* rbf = (const float*)d_in[12];
  const float* rWi = (const float*)d_in[13]; const float* rbi = (const float*)d_in[14];
  const float* rWo = (const float*)d_in[15]; const float* rbo = (const float*)d_in[16];
  const float* rWc = (const float*)d_in[17]; const float* rbc = (const float*)d_in[18];
  const float* nw     = (const float*)d_in[19];
  const float* cscal  = (const float*)d_in[20];
  const float* convw  = (const float*)d_in[21];
  const float* convb  = (const float*)d_in[22];
  float* out = (float*)d_out;

  char* cur = (char*)d_ws;
  auto alloc = [&](size_t bytes) -> void* {
    void* p = cur; cur += (bytes + 255) & ~(size_t)255; return p;
  };
  u16*   Xb     = (u16*)  alloc((size_t)LS*BC*NN*2);      // 6 MB
  float* csum   = (float*)alloc((size_t)64*1024*4);
  float* tmpv   = (float*)alloc(1024*4);
  u16*   anormT = (u16*)  alloc((size_t)NN*NN*2);         // 2 MB
  u16*   Apowb  = (u16*)  alloc((size_t)3*NN*NN*2);       // 6 MB
  float* nbrv   = (float*)alloc(1024*4);
  u16*   effb   = (u16*)  alloc((size_t)3*NN*NN*2);       // 6 MB
  u16*   effbT  = (u16*)  alloc((size_t)3*NN*NN*2);       // 6 MB
  u16*   Wgxb   = (u16*)  alloc((size_t)4096*3072*2);     // 24 MB
  u16*   WgHp   = (u16*)  alloc((size_t)4096*1024*2);     // 8 MB
  u16*   rWgHp  = (u16*)  alloc((size_t)4096*1024*2);     // 8 MB
  u16*   Bcat   = (u16*)  alloc((size_t)8192*1024*2);     // 16 MB: [Cw; rWgx]
  float* bgcat  = (float*)alloc(8192*4);
  u16*   gclb   = (u16*)  alloc((size_t)BC*3072*2);
  u16*   prebuf = (u16*)  alloc((size_t)3072*8192*2);     // 48 MB bf16
  char*  zbase  = cur;
  u16*   Hb2    = (u16*)  alloc((size_t)2*BC*NN*2);
  u16*   rHb2   = (u16*)  alloc((size_t)2*BC*NN*2);
  float* Cs     = (float*)alloc((size_t)BC*NN*4);
  float* rCs    = (float*)alloc((size_t)BC*NN*4);
  size_t zlen   = (size_t)(cur - zbase);
  float* Hfv    = (float*)alloc((size_t)BC*NN*4);
  float* rHfv   = (float*)alloc((size_t)BC*NN*4);
  float* part   = (float*)alloc(64*4*4);

  u16* A1b = Apowb;
  u16* A2b = Apowb + (size_t)NN*NN;
  u16* A3b = Apowb + (size_t)2*NN*NN;
  u16* Cwb   = Bcat;                       // rows 0..4095
  u16* rWgxb = Bcat + (size_t)4096*1024;   // rows 4096..8191

  // fused preprocessing: transpose + colsum1 + packbias + pack
  k_prep<<<592 + (16777216+8388608)/256, 256, 0, stream>>>(
      inputs, adj, Wf, Wi, Wo, Wc, rWf, rWi, rWo, rWc,
      bf_, bi_, bo_, bc_, rbf, rbi, rbo, rbc,
      Xb, csum, Wgxb, WgHp, rWgxb, rWgHp, bgcat);
  k_colsum2<<<4, 256, 0, stream>>>(csum, tmpv);
  dim3 g16(16, 16);
  k_anormT<<<g16, 256, 0, stream>>>(adj, tmpv, A1b, anormT);
  // adjacency powers, 64^2 tiles BK=128
  k_mfma64<<<g16, 256, 0, stream>>>(A1b, anormT, 1024, 1, A2b, 1024);
  k_mfma64<<<g16, 256, 0, stream>>>(A2b, anormT, 1024, 1, A3b, 1024);
  k_nbr<<<NN, 256, 0, stream>>>(A3b, nw, nbrv);
  dim3 geff(16, 48);
  k_effT<<<geff, 256, 0, stream>>>(Apowb, gcw, effb, effbT);

  // Cw = Wgx @ eff (4096x1024, K=3072), 64^2 tiles BK=128 -> 1024 blocks
  dim3 gcwg(16, 64);
  k_mfma64<<<gcwg, 256, 0, stream>>>(Wgxb, effbT, 3072, 0, Cwb, 1024);
  // pre slice 0 only: 128x8192, K=1024
  dim3 gpre0(64, 1);
  k_mfma_nt<<<gpre0, 256, 0, stream>>>(Xb, Bcat, 1024, bgcat, nullptr, prebuf, 8192);
  // last-step gc (for var only)
  dim3 ggcl(48, 2);
  k_mfma64<<<ggcl, 256, 0, stream>>>(Xb + (size_t)(LS-1)*BC*NN, effb, 1024, 0, gclb, 3072);

  hipMemsetAsync(zbase, 0, zlen, stream);

  // 24 fused steps; step t also computes pre-slice t+1 on 64 extra blocks
  for (int t = 0; t < LS; ++t){
    int tn = (t+1 < LS) ? t+1 : t;
    k_step<<<576, 256, 0, stream>>>(WgHp, rWgHp,
        prebuf + (size_t)t*BC*8192,
        Xb + (size_t)tn*BC*NN, Bcat, bgcat,
        prebuf + (size_t)tn*BC*8192, (t+1 < LS) ? 1 : 0,
        nbrv, Hb2, rHb2, Cs, rCs, Hfv, rHfv, t & 1, t == LS-1);
  }

  k_var1<<<64, 256, 0, stream>>>(Xb + (size_t)(LS-1)*BC*NN, gclb, part);
  k_out<<<(64*1024)/256, 256, 0, stream>>>(Hfv, rHfv, part, cscal, convw, convb, out);
}

// Round 9
// 529.591 us; speedup vs baseline: 2.0527x; 2.0527x over previous
//
#include <hip/hip_runtime.h>
#include <cmath>

#define NN 1024
#define BC 128
#define LS 24

typedef unsigned short u16;
typedef __attribute__((ext_vector_type(4))) float f32x4;
typedef __attribute__((ext_vector_type(8))) short bf16x8;
typedef __attribute__((ext_vector_type(8))) unsigned short u16x8;

typedef __attribute__((address_space(1))) const void* as1cv;
typedef __attribute__((address_space(3))) void* as3v;

#define GLD16(gp, lp) __builtin_amdgcn_global_load_lds((as1cv)(gp), (as3v)(lp), 16, 0, 0)

__device__ __forceinline__ float sigf(float x){ return 1.0f/(1.0f+expf(-x)); }

__device__ __forceinline__ u16 f2b(float x){
  union { float f; unsigned u; } v; v.f = x;
  unsigned r = v.u + 0x7FFFu + ((v.u >> 16) & 1u);
  return (u16)(r >> 16);
}
__device__ __forceinline__ float b2f(u16 b){
  union { unsigned u; float f; } v; v.u = ((unsigned)b) << 16;
  return v.f;
}

// ---------------- fused preprocessing ----------------
// blocks [0,512): transpose; [512,576): colsum1; [576,592): packbias; [592,...): pack x8
__global__ void k_prep(const float* __restrict__ inputs, const float* __restrict__ adj,
                       const float* __restrict__ Wf, const float* __restrict__ Wi,
                       const float* __restrict__ Wo, const float* __restrict__ Wc,
                       const float* __restrict__ rWf, const float* __restrict__ rWi,
                       const float* __restrict__ rWo, const float* __restrict__ rWc,
                       const float* __restrict__ bf_, const float* __restrict__ bi_,
                       const float* __restrict__ bo_, const float* __restrict__ bc_,
                       const float* __restrict__ rbf, const float* __restrict__ rbi,
                       const float* __restrict__ rbo, const float* __restrict__ rbc,
                       u16* __restrict__ Xb, float* __restrict__ csum,
                       u16* __restrict__ Wgxb, u16* __restrict__ WgHp,
                       u16* __restrict__ rWgxb, u16* __restrict__ rWgHp,
                       float* __restrict__ bgcat){
  int b = blockIdx.x, tid = threadIdx.x;
  if (b < 512){
    int idx = b*256 + tid;                       // BC*NN
    const float4* p = (const float4*)(inputs + (size_t)idx*LS);
    float v[LS];
    #pragma unroll
    for (int q = 0; q < 6; ++q){
      float4 f = p[q];
      v[q*4]=f.x; v[q*4+1]=f.y; v[q*4+2]=f.z; v[q*4+3]=f.w;
    }
    #pragma unroll
    for (int t = 0; t < LS; ++t)
      Xb[(size_t)t*BC*NN + idx] = f2b(v[t]);
  } else if (b < 576){
    int bb = b - 512;
    for (int j = tid; j < 1024; j += 256){
      float s = 0.f;
      for (int i = 0; i < 16; ++i) s += adj[(size_t)(bb*16+i)*1024 + j];
      csum[(size_t)bb*1024 + j] = s;
    }
  } else if (b < 592){
    int idx = (b-576)*256 + tid;                 // 4096
    int seg = idx >> 10, j = idx & 1023;
    bgcat[idx]      = (seg==0?bf_: seg==1?bi_: seg==2?bo_:bc_)[j];
    bgcat[4096+idx] = (seg==0?rbf: seg==1?rbi: seg==2?rbo:rbc)[j];
  } else {
    int idx = (b-592)*256 + tid;                 // 8-element groups
    if (idx < 2097152){                          // main W: 4096 rows x 512 groups
      int kg = idx & 511, r = idx >> 9;
      int seg = r >> 10, j = r & 1023;
      const float* W = (seg==0?Wf: seg==1?Wi: seg==2?Wo:Wc) + (size_t)j*4096 + kg*8;
      float4 a = *(const float4*)W;
      float4 c = *(const float4*)(W + 4);
      u16x8 o = { f2b(a.x), f2b(a.y), f2b(a.z), f2b(a.w),
                  f2b(c.x), f2b(c.y), f2b(c.z), f2b(c.w) };
      if (kg < 384) *(u16x8*)(Wgxb + (size_t)r*3072 + kg*8) = o;
      else {
        int p = (j>>3)*32 + seg*8 + (j&7);
        *(u16x8*)(WgHp + (size_t)p*1024 + (kg*8 - 3072)) = o;
      }
    } else {
      int g2 = idx - 2097152;                    // rW: 4096 rows x 256 groups
      int kg = g2 & 255, r = g2 >> 8;
      int seg = r >> 10, j = r & 1023;
      const float* W = (seg==0?rWf: seg==1?rWi: seg==2?rWo:rWc) + (size_t)j*2048 + kg*8;
      float4 a = *(const float4*)W;
      float4 c = *(const float4*)(W + 4);
      u16x8 o = { f2b(a.x), f2b(a.y), f2b(a.z), f2b(a.w),
                  f2b(c.x), f2b(c.y), f2b(c.z), f2b(c.w) };
      if (kg < 128) *(u16x8*)(rWgxb + (size_t)r*1024 + kg*8) = o;
      else {
        int p = (j>>3)*32 + seg*8 + (j&7);
        *(u16x8*)(rWgHp + (size_t)p*1024 + (kg*8 - 1024)) = o;
      }
    }
  }
}

__global__ void k_colsum2(const float* __restrict__ part, float* __restrict__ tmp){
  int j = blockIdx.x*256 + threadIdx.x;
  float s = 0.f;
  for (int b = 0; b < 64; ++b) s += part[(size_t)b*1024 + j];
  tmp[j] = (s == 0.f) ? 1e-5f : s;
}

// fused: A1b = bf16(min(tmp[i]*adj,1)); anormT = bf16(tmp[i]*adj)^T
__global__ void k_anormT(const float* __restrict__ adj, const float* __restrict__ tmp,
                         u16* __restrict__ A1b, u16* __restrict__ anormT){
  __shared__ u16 t[64][65];
  int bi = blockIdx.y*64, bj = blockIdx.x*64;
  for (int e = threadIdx.x; e < 4096; e += 256){
    int r = e >> 6, cc = e & 63;
    float v = tmp[bi+r]*adj[(size_t)(bi+r)*1024 + bj+cc];
    A1b[(size_t)(bi+r)*1024 + bj+cc] = f2b(fminf(v, 1.f));
    t[r][cc] = f2b(v);
  }
  __syncthreads();
  for (int e = threadIdx.x; e < 4096; e += 256){
    int r = e >> 6, cc = e & 63;
    anormT[(size_t)(bj+r)*1024 + bi+cc] = t[cc][r];
  }
}

__global__ void k_nbr(const u16* __restrict__ A3b, const float* __restrict__ nw,
                      float* __restrict__ nbr){
  __shared__ float red[256];
  int row = blockIdx.x;
  float s = 0.f;
  for (int j = threadIdx.x; j < 1024; j += 256)
    s += b2f(A3b[(size_t)row*1024 + j])*nw[j];
  red[threadIdx.x] = s; __syncthreads();
  for (int st = 128; st > 0; st >>= 1){
    if (threadIdx.x < st) red[threadIdx.x] += red[threadIdx.x+st];
    __syncthreads();
  }
  if (threadIdx.x == 0) nbr[row] = red[0];
}

__global__ void k_effT(const u16* __restrict__ Ap, const float* __restrict__ gcw,
                       u16* __restrict__ effb, u16* __restrict__ effbT){
  __shared__ u16 t[64][65];
  int bi = blockIdx.y*64, bj = blockIdx.x*64;   // bi over 3072, bj over 1024
  for (int e = threadIdx.x; e < 4096; e += 256){
    int r = e >> 6, cc = e & 63;
    size_t idx = (size_t)(bi+r)*1024 + bj+cc;
    u16 v = f2b(b2f(Ap[idx]) * gcw[idx]);
    effb[idx] = v;
    t[r][cc] = v;
  }
  __syncthreads();
  for (int e = threadIdx.x; e < 4096; e += 256){
    int r = e >> 6, cc = e & 63;
    effbT[(size_t)(bj+r)*3072 + bi+cc] = t[cc][r];
  }
}

// ---------------- bf16 MFMA NT GEMM, 128x128 tile (m97 structure) ----------------
__device__ __forceinline__ void mfma_tile(
    const u16* __restrict__ A, const u16* __restrict__ Bw, int K,
    const float* __restrict__ bias,
    float* __restrict__ outf, u16* __restrict__ outb, int ldc,
    u16* ldsA, u16* ldsB)
{
  const int tid  = threadIdx.x;
  const int lane = tid & 63;
  const int w    = tid >> 6;
  const int wr   = (w >> 1) * 64;
  const int wc   = (w & 1) * 64;
  f32x4 acc[4][4] = {};

  const int lrow = lane >> 3;
  const int srck = ((lane & 7) ^ lrow) * 8;
  for (int k0 = 0; k0 < K; k0 += 64){
    #pragma unroll
    for (int c = 0; c < 4; ++c){
      int row = w*32 + c*8;
      GLD16(A  + (size_t)(row + lrow)*K + k0 + srck, &ldsA[row*64]);
      GLD16(Bw + (size_t)(row + lrow)*K + k0 + srck, &ldsB[row*64]);
    }
    __syncthreads();
    #pragma unroll
    for (int kk = 0; kk < 2; ++kk) {
      bf16x8 af[4], bfr[4];
      #pragma unroll
      for (int mi = 0; mi < 4; ++mi) {
        int row = wr + mi*16 + (lane & 15);
        int grp = (kk*4 + (lane >> 4)) ^ (row & 7);
        af[mi] = *(const bf16x8*)&ldsA[row*64 + grp*8];
      }
      #pragma unroll
      for (int ni = 0; ni < 4; ++ni) {
        int row = wc + ni*16 + (lane & 15);
        int grp = (kk*4 + (lane >> 4)) ^ (row & 7);
        bfr[ni] = *(const bf16x8*)&ldsB[row*64 + grp*8];
      }
      #pragma unroll
      for (int mi = 0; mi < 4; ++mi)
        #pragma unroll
        for (int ni = 0; ni < 4; ++ni)
          acc[mi][ni] = __builtin_amdgcn_mfma_f32_16x16x32_bf16(af[mi], bfr[ni], acc[mi][ni], 0, 0, 0);
    }
    __syncthreads();
  }
  #pragma unroll
  for (int mi = 0; mi < 4; ++mi) {
    #pragma unroll
    for (int ni = 0; ni < 4; ++ni) {
      int col = wc + ni*16 + (lane & 15);
      #pragma unroll
      for (int q = 0; q < 4; ++q) {
        int row = wr + mi*16 + (lane >> 4)*4 + q;
        float v = acc[mi][ni][q];
        if (bias) v += bias[col];
        if (outf) outf[(size_t)row*ldc + col] = v;
        if (outb) outb[(size_t)row*ldc + col] = f2b(v);
      }
    }
  }
}

// pre = X @ Bcat^T + bgcat, grid (64,24), XCD-swizzled: each XCD owns 8 B-panels (2 MB, L2-fit)
__global__ __launch_bounds__(256) void k_mfma_pre(
    const u16* __restrict__ Xb, const u16* __restrict__ Bcat,
    const float* __restrict__ bgcat, u16* __restrict__ prebuf)
{
  __shared__ u16 lds[16384];
  int id = blockIdx.y*64 + blockIdx.x;
  int bx = (id & 7)*8 + ((id >> 3) & 7);   // [0,64)
  int by = id >> 6;                        // [0,24)
  mfma_tile(Xb + (size_t)by*128*1024, Bcat + (size_t)bx*128*1024, 1024,
            bgcat + bx*128, nullptr,
            prebuf + (size_t)by*128*8192 + bx*128, 8192,
            lds, lds + 8192);
}

// ---------------- 64x64-tile NT GEMM, BK=128 (32 KB LDS) ----------------
__global__ __launch_bounds__(256) void k_mfma64(
    const u16* __restrict__ Ag, const u16* __restrict__ Bg, int K,
    int clamp1, int swz, u16* __restrict__ outb, int ldc)
{
  __shared__ u16 ldsA[64*128];   // 16 KB
  __shared__ u16 ldsB[64*128];   // 16 KB
  const int tid  = threadIdx.x;
  const int lane = tid & 63;
  const int w    = tid >> 6;
  const int wr   = (w >> 1) * 32;
  const int wc   = (w & 1) * 32;
  int bx = blockIdx.x, by = blockIdx.y;
  if (swz){  // valid for grid (16,64): each XCD owns an 8-panel A-stripe (3 MB, L2-fit)
    int id = by*16 + bx;
    by = (id & 7)*8 + ((id >> 3) & 7);   // [0,64)
    bx = id >> 6;                        // [0,16)
  }
  const u16* A = Ag + (size_t)by*64*K;
  const u16* B = Bg + (size_t)bx*64*K;
  f32x4 acc[2][2] = {};

  const int r4  = lane >> 4;
  const int g16 = lane & 15;
  for (int k0 = 0; k0 < K; k0 += 128){
    #pragma unroll
    for (int c = 0; c < 4; ++c){
      int rowb = w*16 + c*4;
      int row = rowb + r4;
      int srcg = (g16 & 8) | ((g16 & 7) ^ (row & 7));
      GLD16(A + (size_t)row*K + k0 + srcg*8, &ldsA[rowb*128]);
      GLD16(B + (size_t)row*K + k0 + srcg*8, &ldsB[rowb*128]);
    }
    __syncthreads();
    #pragma unroll
    for (int kk = 0; kk < 4; ++kk){
      int idx = kk*4 + (lane >> 4);
      bf16x8 af[2], bfr[2];
      #pragma unroll
      for (int mi = 0; mi < 2; ++mi){
        int row = wr + mi*16 + (lane & 15);
        int pa = (idx & 8) | ((idx & 7) ^ (row & 7));
        af[mi] = *(const bf16x8*)&ldsA[row*128 + pa*8];
      }
      #pragma unroll
      for (int ni = 0; ni < 2; ++ni){
        int row = wc + ni*16 + (lane & 15);
        int pb = (idx & 8) | ((idx & 7) ^ (row & 7));
        bfr[ni] = *(const bf16x8*)&ldsB[row*128 + pb*8];
      }
      #pragma unroll
      for (int mi = 0; mi < 2; ++mi)
        #pragma unroll
        for (int ni = 0; ni < 2; ++ni)
          acc[mi][ni] = __builtin_amdgcn_mfma_f32_16x16x32_bf16(af[mi], bfr[ni], acc[mi][ni], 0, 0, 0);
    }
    __syncthreads();
  }
  #pragma unroll
  for (int mi = 0; mi < 2; ++mi){
    #pragma unroll
    for (int ni = 0; ni < 2; ++ni){
      int col = bx*64 + wc + ni*16 + (lane & 15);
      #pragma unroll
      for (int q = 0; q < 4; ++q){
        int row = by*64 + wr + mi*16 + (lane >> 4)*4 + q;
        float v = acc[mi][ni][q];
        if (clamp1) v = fminf(v, 1.f);
        outb[(size_t)row*ldc + col] = f2b(v);
      }
    }
  }
}

// ---------------- fused per-step kernel: 512 blocks ----------------
// job = bid>>8; rem = bid&255; s = rem>>1 (8 gate cells x 4 segs = 32 packed cols);
// r0 = (rem&1)*64. GEMM M=64, N=32, K=1024, BK=256.
__global__ __launch_bounds__(256) void k_step(
    const u16* __restrict__ WgHp, const u16* __restrict__ rWgHp,
    const u16* __restrict__ pre_t,           // [BC][8192] bf16; job*4096 col offset
    const float* __restrict__ nbrv,
    u16* __restrict__ Hb2, u16* __restrict__ rHb2,
    float* __restrict__ Cs, float* __restrict__ rCs,
    float* __restrict__ Hf, float* __restrict__ rHf,
    int ph, int last)
{
  __shared__ u16 ldsA[64*256];   // 32 KB
  __shared__ u16 ldsB[32*256];   // 16 KB

  const int tid  = threadIdx.x;
  const int lane = tid & 63;
  const int w    = tid >> 6;          // 0..3
  const int bid  = blockIdx.x;
  const int job  = bid >> 8;
  const int rem  = bid & 255;
  const int s    = rem >> 1;
  const int r0   = (rem & 1) * 64;

  const u16* Bp   = (job ? rWgHp : WgHp) + (size_t)s*32*1024;
  const u16* Ab   = (job ? rHb2 : Hb2) + (size_t)ph*BC*NN + (size_t)r0*NN;
  const u16* pret = pre_t + (size_t)job*4096;
  u16* Hnext  = (job ? rHb2 : Hb2) + (size_t)(ph^1)*BC*NN;
  float* Csb  = job ? rCs : Cs;
  float* Hfin = job ? rHf : Hf;

  const int g32   = lane & 31;       // 16B group within 512B row
  const int rhalf = lane >> 5;       // 0..1 row offset within issue

  f32x4 acc[2] = {};
  for (int t = 0; t < 4; ++t){
    int k0 = t*256;
    #pragma unroll
    for (int c = 0; c < 8; ++c){
      int rowb = w*16 + c*2;
      int row = rowb + rhalf;
      int srcg = (g32 & 24) | ((g32 & 7) ^ (row & 7));
      GLD16(Ab + (size_t)row*1024 + k0 + srcg*8, &ldsA[rowb*256]);
    }
    #pragma unroll
    for (int c = 0; c < 4; ++c){
      int rowb = w*8 + c*2;
      int row = rowb + rhalf;
      int srcg = (g32 & 24) | ((g32 & 7) ^ (row & 7));
      GLD16(Bp + (size_t)row*1024 + k0 + srcg*8, &ldsB[rowb*256]);
    }
    __syncthreads();
    #pragma unroll
    for (int kk = 0; kk < 8; ++kk){
      int idx = kk*4 + (lane >> 4);
      int rowa = w*16 + (lane & 15);
      int pa = (idx & 24) | ((idx & 7) ^ (rowa & 7));
      bf16x8 af = *(const bf16x8*)&ldsA[rowa*256 + pa*8];
      #pragma unroll
      for (int ni = 0; ni < 2; ++ni){
        int rowb2 = ni*16 + (lane & 15);
        int pb = (idx & 24) | ((idx & 7) ^ (rowb2 & 7));
        bf16x8 bv = *(const bf16x8*)&ldsB[rowb2*256 + pb*8];
        acc[ni] = __builtin_amdgcn_mfma_f32_16x16x32_bf16(af, bv, acc[ni], 0, 0, 0);
      }
    }
    __syncthreads();
  }

  // epilogue: + pre, gates via shfl_xor(8) (round-4/8 verified mapping)
  #pragma unroll
  for (int ni = 0; ni < 2; ++ni){
    int pcol = ni*16 + (lane & 15);
    int gcol = (pcol >> 3)*1024 + s*8 + (pcol & 7);
    #pragma unroll
    for (int q = 0; q < 4; ++q){
      int row = r0 + w*16 + (lane >> 4)*4 + q;
      acc[ni][q] += b2f(pret[(size_t)row*8192 + gcol]);
    }
  }
  const bool act = (lane & 15) < 8;
  const int  c   = lane & 7;
  const int  col = s*8 + c;
  float fac = 1.f;
  if (!job && act) fac = nbrv[col];
  #pragma unroll
  for (int q = 0; q < 4; ++q){
    float a0 = acc[0][q], a1 = acc[1][q];
    float p1 = __shfl_xor(a0, 8);   // seg1 (i-gate)
    float p3 = __shfl_xor(a1, 8);   // seg3 (Ct)
    if (act){
      int row = r0 + w*16 + (lane >> 4)*4 + q;
      float fg = sigf(a0), ig = sigf(p1), og = sigf(a1), ct = tanhf(p3);
      size_t cidx = (size_t)row*NN + col;
      float cs = fg*Csb[cidx]*fac + ig*ct;
      Csb[cidx] = cs;
      float h = og*tanhf(cs);
      Hnext[cidx] = f2b(h);
      if (last) Hfin[cidx] = h;
    }
  }
}

// ---------------- last-step statistics ----------------
__global__ void k_var1(const u16* __restrict__ Xl, const u16* __restrict__ gcl,
                       float* __restrict__ part){
  int ch = blockIdx.x & 1, seg = blockIdx.x >> 1;   // 64 blocks
  int tid = threadIdx.x;
  float s1=0.f,q1=0.f,s2=0.f,q2=0.f;
  for (int bb = 0; bb < 2; ++bb){
    int row = (seg*2+bb)*2 + ch;
    const u16* xr = Xl + (size_t)row*1024;
    for (int n = tid; n < 1024; n += 256){ float v = b2f(xr[n]); s1 += v; q1 += v*v; }
    const u16* gr = gcl + (size_t)row*3072;
    for (int n = tid; n < 3072; n += 256){ float v = b2f(gr[n]); s2 += v; q2 += v*v; }
  }
  __shared__ float red[256][4];
  red[tid][0]=s1; red[tid][1]=q1; red[tid][2]=s2; red[tid][3]=q2;
  __syncthreads();
  for (int st = 128; st > 0; st >>= 1){
    if (tid < st){ for (int z = 0; z < 4; ++z) red[tid][z] += red[tid+st][z]; }
    __syncthreads();
  }
  if (tid == 0){ for (int z = 0; z < 4; ++z) part[(size_t)blockIdx.x*4 + z] = red[0][z]; }
}

// fused var2 + pred + conv: one thread per (b,n), 256 blocks
__global__ void k_out(const float* __restrict__ H, const float* __restrict__ rH,
                      const float* __restrict__ part, const float* __restrict__ cptr,
                      const float* __restrict__ cw, const float* __restrict__ cb,
                      float* __restrict__ out){
  __shared__ float vsh[4];
  int tid = threadIdx.x;
  if (tid < 4){
    int ch = tid & 1, which = tid >> 1;   // which: 0=var1, 1=var2
    float s = 0.f, q = 0.f;
    for (int seg = 0; seg < 32; ++seg){
      const float* p = part + (size_t)(seg*2+ch)*4 + which*2;
      s += p[0]; q += p[1];
    }
    float n = which ? 196608.f : 65536.f;
    vsh[tid] = (q - s*s/n) / (n - 1.f);
  }
  __syncthreads();
  int idx = blockIdx.x*256 + tid;   // 64*1024
  int n = idx & 1023, b = idx >> 10;
  float c0 = cptr[0];
  float v10 = vsh[0], v11 = vsh[1], v20 = vsh[2], v21 = vsh[3];
  size_t i0 = (size_t)(b*2+0)*1024 + n, i1 = (size_t)(b*2+1)*1024 + n;
  float p0 = (H[i0]*v10*c0 + rH[i0]*v20) / (v10 + v20*c0);
  float p1 = (H[i1]*v11*c0 + rH[i1]*v21) / (v11 + v21*c0);
  float* ob = out + (size_t)b*24*1024 + n;
  #pragma unroll
  for (int o = 0; o < 24; ++o)
    ob[(size_t)o*1024] = p0*cw[o*2+0] + p1*cw[o*2+1] + cb[o];
}

// ---------------- launch ----------------
extern "C" void kernel_launch(void* const* d_in, const int* in_sizes, int n_in,
                              void* d_out, int out_size, void* d_ws, size_t ws_size,
                              hipStream_t stream) {
  const float* inputs = (const float*)d_in[0];
  const float* adj    = (const float*)d_in[1];
  const float* gcw    = (const float*)d_in[2];
  const float* Wf  = (const float*)d_in[3];  const float* bf_ = (const float*)d_in[4];
  const float* Wi  = (const float*)d_in[5];  const float* bi_ = (const float*)d_in[6];
  const float* Wo  = (const float*)d_in[7];  const float* bo_ = (const float*)d_in[8];
  const float* Wc  = (const float*)d_in[9];  const float* bc_ = (const float*)d_in[10];
  const float* rWf = (const float*)d_in[11]; const float* rbf = (const float*)d_in[12];
  const float* rWi = (const float*)d_in[13]; const float* rbi = (const float*)d_in[14];
  const float* rWo = (const float*)d_in[15]; const float* rbo = (const float*)d_in[16];
  const float* rWc = (const float*)d_in[17]; const float* rbc = (const float*)d_in[18];
  const float* nw     = (const float*)d_in[19];
  const float* cscal  = (const float*)d_in[20];
  const float* convw  = (const float*)d_in[21];
  const float* convb  = (const float*)d_in[22];
  float* out = (float*)d_out;

  char* cur = (char*)d_ws;
  auto alloc = [&](size_t bytes) -> void* {
    void* p = cur; cur += (bytes + 255) & ~(size_t)255; return p;
  };
  u16*   Xb     = (u16*)  alloc((size_t)LS*BC*NN*2);      // 6 MB
  float* csum   = (float*)alloc((size_t)64*1024*4);
  float* tmpv   = (float*)alloc(1024*4);
  u16*   anormT = (u16*)  alloc((size_t)NN*NN*2);         // 2 MB
  u16*   Apowb  = (u16*)  alloc((size_t)3*NN*NN*2);       // 6 MB
  float* nbrv   = (float*)alloc(1024*4);
  u16*   effb   = (u16*)  alloc((size_t)3*NN*NN*2);       // 6 MB
  u16*   effbT  = (u16*)  alloc((size_t)3*NN*NN*2);       // 6 MB
  u16*   Wgxb   = (u16*)  alloc((size_t)4096*3072*2);     // 24 MB
  u16*   WgHp   = (u16*)  alloc((size_t)4096*1024*2);     // 8 MB
  u16*   rWgHp  = (u16*)  alloc((size_t)4096*1024*2);     // 8 MB
  u16*   Bcat   = (u16*)  alloc((size_t)8192*1024*2);     // 16 MB: [Cw; rWgx]
  float* bgcat  = (float*)alloc(8192*4);
  u16*   gclb   = (u16*)  alloc((size_t)BC*3072*2);
  u16*   prebuf = (u16*)  alloc((size_t)3072*8192*2);     // 48 MB bf16
  char*  zbase  = cur;
  u16*   Hb2    = (u16*)  alloc((size_t)2*BC*NN*2);
  u16*   rHb2   = (u16*)  alloc((size_t)2*BC*NN*2);
  float* Cs     = (float*)alloc((size_t)BC*NN*4);
  float* rCs    = (float*)alloc((size_t)BC*NN*4);
  size_t zlen   = (size_t)(cur - zbase);
  float* Hfv    = (float*)alloc((size_t)BC*NN*4);
  float* rHfv   = (float*)alloc((size_t)BC*NN*4);
  float* part   = (float*)alloc(64*4*4);

  u16* A1b = Apowb;
  u16* A2b = Apowb + (size_t)NN*NN;
  u16* A3b = Apowb + (size_t)2*NN*NN;
  u16* Cwb   = Bcat;                       // rows 0..4095
  u16* rWgxb = Bcat + (size_t)4096*1024;   // rows 4096..8191

  // fused preprocessing: transpose + colsum1 + packbias + pack (8 elems/thread)
  k_prep<<<592 + (2097152+1048576)/256, 256, 0, stream>>>(
      inputs, adj, Wf, Wi, Wo, Wc, rWf, rWi, rWo, rWc,
      bf_, bi_, bo_, bc_, rbf, rbi, rbo, rbc,
      Xb, csum, Wgxb, WgHp, rWgxb, rWgHp, bgcat);
  k_colsum2<<<4, 256, 0, stream>>>(csum, tmpv);
  dim3 g16(16, 16);
  k_anormT<<<g16, 256, 0, stream>>>(adj, tmpv, A1b, anormT);
  // adjacency powers, 64^2 tiles BK=128
  k_mfma64<<<g16, 256, 0, stream>>>(A1b, anormT, 1024, 1, 0, A2b, 1024);
  k_mfma64<<<g16, 256, 0, stream>>>(A2b, anormT, 1024, 1, 0, A3b, 1024);
  k_nbr<<<NN, 256, 0, stream>>>(A3b, nw, nbrv);
  dim3 geff(16, 48);
  k_effT<<<geff, 256, 0, stream>>>(Apowb, gcw, effb, effbT);

  // Cw = Wgx @ eff (4096x1024, K=3072), XCD-swizzled (grid (16,64))
  dim3 gcwg(16, 64);
  k_mfma64<<<gcwg, 256, 0, stream>>>(Wgxb, effbT, 3072, 0, 1, Cwb, 1024);
  // pre = X @ [Cw; rWgx]^T + biascat (3072x8192, K=1024), XCD-swizzled
  dim3 gpre(64, 24);
  k_mfma_pre<<<gpre, 256, 0, stream>>>(Xb, Bcat, bgcat, prebuf);
  // last-step gc (for var only)
  dim3 ggcl(48, 2);
  k_mfma64<<<ggcl, 256, 0, stream>>>(Xb + (size_t)(LS-1)*BC*NN, effb, 1024, 0, 0, gclb, 3072);

  hipMemsetAsync(zbase, 0, zlen, stream);

  // 24 fused steps
  for (int t = 0; t < LS; ++t)
    k_step<<<512, 256, 0, stream>>>(WgHp, rWgHp,
        prebuf + (size_t)t*BC*8192,
        nbrv, Hb2, rHb2, Cs, rCs, Hfv, rHfv, t & 1, t == LS-1);

  k_var1<<<64, 256, 0, stream>>>(Xb + (size_t)(LS-1)*BC*NN, gclb, part);
  k_out<<<(64*1024)/256, 256, 0, stream>>>(Hfv, rHfv, part, cscal, convw, convb, out);
}

// Round 10
// 529.339 us; speedup vs baseline: 2.0536x; 1.0005x over previous
//
#include <hip/hip_runtime.h>
#include <cmath>

#define NN 1024
#define BC 128
#define LS 24

typedef unsigned short u16;
typedef __attribute__((ext_vector_type(4))) float f32x4;
typedef __attribute__((ext_vector_type(8))) short bf16x8;
typedef __attribute__((ext_vector_type(8))) unsigned short u16x8;

typedef __attribute__((address_space(1))) const void* as1cv;
typedef __attribute__((address_space(3))) void* as3v;

#define GLD16(gp, lp) __builtin_amdgcn_global_load_lds((as1cv)(gp), (as3v)(lp), 16, 0, 0)

__device__ __forceinline__ float sigf(float x){ return 1.0f/(1.0f+expf(-x)); }

__device__ __forceinline__ u16 f2b(float x){
  union { float f; unsigned u; } v; v.f = x;
  unsigned r = v.u + 0x7FFFu + ((v.u >> 16) & 1u);
  return (u16)(r >> 16);
}
__device__ __forceinline__ float b2f(u16 b){
  union { unsigned u; float f; } v; v.u = ((unsigned)b) << 16;
  return v.f;
}

// ---------------- fused preprocessing ----------------
// blocks [0,512): transpose; [512,576): colsum1; [576,592): packbias; [592,...): pack x8
__global__ void k_prep(const float* __restrict__ inputs, const float* __restrict__ adj,
                       const float* __restrict__ Wf, const float* __restrict__ Wi,
                       const float* __restrict__ Wo, const float* __restrict__ Wc,
                       const float* __restrict__ rWf, const float* __restrict__ rWi,
                       const float* __restrict__ rWo, const float* __restrict__ rWc,
                       const float* __restrict__ bf_, const float* __restrict__ bi_,
                       const float* __restrict__ bo_, const float* __restrict__ bc_,
                       const float* __restrict__ rbf, const float* __restrict__ rbi,
                       const float* __restrict__ rbo, const float* __restrict__ rbc,
                       u16* __restrict__ Xb, float* __restrict__ csum,
                       u16* __restrict__ Wgxb, u16* __restrict__ WgHp,
                       u16* __restrict__ rWgxb, u16* __restrict__ rWgHp,
                       float* __restrict__ bgcat){
  int b = blockIdx.x, tid = threadIdx.x;
  if (b < 512){
    int idx = b*256 + tid;                       // BC*NN
    const float4* p = (const float4*)(inputs + (size_t)idx*LS);
    float v[LS];
    #pragma unroll
    for (int q = 0; q < 6; ++q){
      float4 f = p[q];
      v[q*4]=f.x; v[q*4+1]=f.y; v[q*4+2]=f.z; v[q*4+3]=f.w;
    }
    #pragma unroll
    for (int t = 0; t < LS; ++t)
      Xb[(size_t)t*BC*NN + idx] = f2b(v[t]);
  } else if (b < 576){
    int bb = b - 512;
    for (int j = tid; j < 1024; j += 256){
      float s = 0.f;
      for (int i = 0; i < 16; ++i) s += adj[(size_t)(bb*16+i)*1024 + j];
      csum[(size_t)bb*1024 + j] = s;
    }
  } else if (b < 592){
    int idx = (b-576)*256 + tid;                 // 4096
    int seg = idx >> 10, j = idx & 1023;
    bgcat[idx]      = (seg==0?bf_: seg==1?bi_: seg==2?bo_:bc_)[j];
    bgcat[4096+idx] = (seg==0?rbf: seg==1?rbi: seg==2?rbo:rbc)[j];
  } else {
    int idx = (b-592)*256 + tid;                 // 8-element groups
    if (idx < 2097152){                          // main W: 4096 rows x 512 groups
      int kg = idx & 511, r = idx >> 9;
      int seg = r >> 10, j = r & 1023;
      const float* W = (seg==0?Wf: seg==1?Wi: seg==2?Wo:Wc) + (size_t)j*4096 + kg*8;
      float4 a = *(const float4*)W;
      float4 c = *(const float4*)(W + 4);
      u16x8 o = { f2b(a.x), f2b(a.y), f2b(a.z), f2b(a.w),
                  f2b(c.x), f2b(c.y), f2b(c.z), f2b(c.w) };
      if (kg < 384) *(u16x8*)(Wgxb + (size_t)r*3072 + kg*8) = o;
      else {
        int p = (j>>3)*32 + seg*8 + (j&7);
        *(u16x8*)(WgHp + (size_t)p*1024 + (kg*8 - 3072)) = o;
      }
    } else {
      int g2 = idx - 2097152;                    // rW: 4096 rows x 256 groups
      int kg = g2 & 255, r = g2 >> 8;
      int seg = r >> 10, j = r & 1023;
      const float* W = (seg==0?rWf: seg==1?rWi: seg==2?rWo:rWc) + (size_t)j*2048 + kg*8;
      float4 a = *(const float4*)W;
      float4 c = *(const float4*)(W + 4);
      u16x8 o = { f2b(a.x), f2b(a.y), f2b(a.z), f2b(a.w),
                  f2b(c.x), f2b(c.y), f2b(c.z), f2b(c.w) };
      if (kg < 128) *(u16x8*)(rWgxb + (size_t)r*1024 + kg*8) = o;
      else {
        int p = (j>>3)*32 + seg*8 + (j&7);
        *(u16x8*)(rWgHp + (size_t)p*1024 + (kg*8 - 1024)) = o;
      }
    }
  }
}

__global__ void k_colsum2(const float* __restrict__ part, float* __restrict__ tmp){
  int j = blockIdx.x*256 + threadIdx.x;
  float s = 0.f;
  for (int b = 0; b < 64; ++b) s += part[(size_t)b*1024 + j];
  tmp[j] = (s == 0.f) ? 1e-5f : s;
}

// fused: A1b = bf16(min(tmp[i]*adj,1)); anormT = bf16(tmp[i]*adj)^T
__global__ void k_anormT(const float* __restrict__ adj, const float* __restrict__ tmp,
                         u16* __restrict__ A1b, u16* __restrict__ anormT){
  __shared__ u16 t[64][65];
  int bi = blockIdx.y*64, bj = blockIdx.x*64;
  for (int e = threadIdx.x; e < 4096; e += 256){
    int r = e >> 6, cc = e & 63;
    float v = tmp[bi+r]*adj[(size_t)(bi+r)*1024 + bj+cc];
    A1b[(size_t)(bi+r)*1024 + bj+cc] = f2b(fminf(v, 1.f));
    t[r][cc] = f2b(v);
  }
  __syncthreads();
  for (int e = threadIdx.x; e < 4096; e += 256){
    int r = e >> 6, cc = e & 63;
    anormT[(size_t)(bj+r)*1024 + bi+cc] = t[cc][r];
  }
}

__global__ void k_nbr(const u16* __restrict__ A3b, const float* __restrict__ nw,
                      float* __restrict__ nbr){
  __shared__ float red[256];
  int row = blockIdx.x;
  float s = 0.f;
  for (int j = threadIdx.x; j < 1024; j += 256)
    s += b2f(A3b[(size_t)row*1024 + j])*nw[j];
  red[threadIdx.x] = s; __syncthreads();
  for (int st = 128; st > 0; st >>= 1){
    if (threadIdx.x < st) red[threadIdx.x] += red[threadIdx.x+st];
    __syncthreads();
  }
  if (threadIdx.x == 0) nbr[row] = red[0];
}

__global__ void k_effT(const u16* __restrict__ Ap, const float* __restrict__ gcw,
                       u16* __restrict__ effb, u16* __restrict__ effbT){
  __shared__ u16 t[64][65];
  int bi = blockIdx.y*64, bj = blockIdx.x*64;   // bi over 3072, bj over 1024
  for (int e = threadIdx.x; e < 4096; e += 256){
    int r = e >> 6, cc = e & 63;
    size_t idx = (size_t)(bi+r)*1024 + bj+cc;
    u16 v = f2b(b2f(Ap[idx]) * gcw[idx]);
    effb[idx] = v;
    t[r][cc] = v;
  }
  __syncthreads();
  for (int e = threadIdx.x; e < 4096; e += 256){
    int r = e >> 6, cc = e & 63;
    effbT[(size_t)(bj+r)*3072 + bi+cc] = t[cc][r];
  }
}

// ---------------- bf16 MFMA NT GEMM, 128x128 tile (m97 structure) ----------------
__device__ __forceinline__ void mfma_tile(
    const u16* __restrict__ A, const u16* __restrict__ Bw, int K,
    const float* __restrict__ bias,
    float* __restrict__ outf, u16* __restrict__ outb, int ldc,
    u16* ldsA, u16* ldsB)
{
  const int tid  = threadIdx.x;
  const int lane = tid & 63;
  const int w    = tid >> 6;
  const int wr   = (w >> 1) * 64;
  const int wc   = (w & 1) * 64;
  f32x4 acc[4][4] = {};

  const int lrow = lane >> 3;
  const int srck = ((lane & 7) ^ lrow) * 8;
  for (int k0 = 0; k0 < K; k0 += 64){
    #pragma unroll
    for (int c = 0; c < 4; ++c){
      int row = w*32 + c*8;
      GLD16(A  + (size_t)(row + lrow)*K + k0 + srck, &ldsA[row*64]);
      GLD16(Bw + (size_t)(row + lrow)*K + k0 + srck, &ldsB[row*64]);
    }
    __syncthreads();
    #pragma unroll
    for (int kk = 0; kk < 2; ++kk) {
      bf16x8 af[4], bfr[4];
      #pragma unroll
      for (int mi = 0; mi < 4; ++mi) {
        int row = wr + mi*16 + (lane & 15);
        int grp = (kk*4 + (lane >> 4)) ^ (row & 7);
        af[mi] = *(const bf16x8*)&ldsA[row*64 + grp*8];
      }
      #pragma unroll
      for (int ni = 0; ni < 4; ++ni) {
        int row = wc + ni*16 + (lane & 15);
        int grp = (kk*4 + (lane >> 4)) ^ (row & 7);
        bfr[ni] = *(const bf16x8*)&ldsB[row*64 + grp*8];
      }
      #pragma unroll
      for (int mi = 0; mi < 4; ++mi)
        #pragma unroll
        for (int ni = 0; ni < 4; ++ni)
          acc[mi][ni] = __builtin_amdgcn_mfma_f32_16x16x32_bf16(af[mi], bfr[ni], acc[mi][ni], 0, 0, 0);
    }
    __syncthreads();
  }
  #pragma unroll
  for (int mi = 0; mi < 4; ++mi) {
    #pragma unroll
    for (int ni = 0; ni < 4; ++ni) {
      int col = wc + ni*16 + (lane & 15);
      #pragma unroll
      for (int q = 0; q < 4; ++q) {
        int row = wr + mi*16 + (lane >> 4)*4 + q;
        float v = acc[mi][ni][q];
        if (bias) v += bias[col];
        if (outf) outf[(size_t)row*ldc + col] = v;
        if (outb) outb[(size_t)row*ldc + col] = f2b(v);
      }
    }
  }
}

// pre = X @ Bcat^T + bgcat, grid (64,24), XCD-swizzled: each XCD owns 8 B-panels (2 MB, L2-fit)
__global__ __launch_bounds__(256) void k_mfma_pre(
    const u16* __restrict__ Xb, const u16* __restrict__ Bcat,
    const float* __restrict__ bgcat, u16* __restrict__ prebuf)
{
  __shared__ u16 lds[16384];
  int id = blockIdx.y*64 + blockIdx.x;
  int bx = (id & 7)*8 + ((id >> 3) & 7);   // [0,64)
  int by = id >> 6;                        // [0,24)
  mfma_tile(Xb + (size_t)by*128*1024, Bcat + (size_t)bx*128*1024, 1024,
            bgcat + bx*128, nullptr,
            prebuf + (size_t)by*128*8192 + bx*128, 8192,
            lds, lds + 8192);
}

// ---------------- 64x64-tile NT GEMM, BK=128 (32 KB LDS) ----------------
__global__ __launch_bounds__(256) void k_mfma64(
    const u16* __restrict__ Ag, const u16* __restrict__ Bg, int K,
    int clamp1, int swz, u16* __restrict__ outb, int ldc)
{
  __shared__ u16 ldsA[64*128];   // 16 KB
  __shared__ u16 ldsB[64*128];   // 16 KB
  const int tid  = threadIdx.x;
  const int lane = tid & 63;
  const int w    = tid >> 6;
  const int wr   = (w >> 1) * 32;
  const int wc   = (w & 1) * 32;
  int bx = blockIdx.x, by = blockIdx.y;
  if (swz){  // valid for grid (16,64): each XCD owns an 8-panel A-stripe (3 MB, L2-fit)
    int id = by*16 + bx;
    by = (id & 7)*8 + ((id >> 3) & 7);   // [0,64)
    bx = id >> 6;                        // [0,16)
  }
  const u16* A = Ag + (size_t)by*64*K;
  const u16* B = Bg + (size_t)bx*64*K;
  f32x4 acc[2][2] = {};

  const int r4  = lane >> 4;
  const int g16 = lane & 15;
  for (int k0 = 0; k0 < K; k0 += 128){
    #pragma unroll
    for (int c = 0; c < 4; ++c){
      int rowb = w*16 + c*4;
      int row = rowb + r4;
      int srcg = (g16 & 8) | ((g16 & 7) ^ (row & 7));
      GLD16(A + (size_t)row*K + k0 + srcg*8, &ldsA[rowb*128]);
      GLD16(B + (size_t)row*K + k0 + srcg*8, &ldsB[rowb*128]);
    }
    __syncthreads();
    #pragma unroll
    for (int kk = 0; kk < 4; ++kk){
      int idx = kk*4 + (lane >> 4);
      bf16x8 af[2], bfr[2];
      #pragma unroll
      for (int mi = 0; mi < 2; ++mi){
        int row = wr + mi*16 + (lane & 15);
        int pa = (idx & 8) | ((idx & 7) ^ (row & 7));
        af[mi] = *(const bf16x8*)&ldsA[row*128 + pa*8];
      }
      #pragma unroll
      for (int ni = 0; ni < 2; ++ni){
        int row = wc + ni*16 + (lane & 15);
        int pb = (idx & 8) | ((idx & 7) ^ (row & 7));
        bfr[ni] = *(const bf16x8*)&ldsB[row*128 + pb*8];
      }
      #pragma unroll
      for (int mi = 0; mi < 2; ++mi)
        #pragma unroll
        for (int ni = 0; ni < 2; ++ni)
          acc[mi][ni] = __builtin_amdgcn_mfma_f32_16x16x32_bf16(af[mi], bfr[ni], acc[mi][ni], 0, 0, 0);
    }
    __syncthreads();
  }
  #pragma unroll
  for (int mi = 0; mi < 2; ++mi){
    #pragma unroll
    for (int ni = 0; ni < 2; ++ni){
      int col = bx*64 + wc + ni*16 + (lane & 15);
      #pragma unroll
      for (int q = 0; q < 4; ++q){
        int row = by*64 + wr + mi*16 + (lane >> 4)*4 + q;
        float v = acc[mi][ni][q];
        if (clamp1) v = fminf(v, 1.f);
        outb[(size_t)row*ldc + col] = f2b(v);
      }
    }
  }
}

// ---------------- fused per-step kernel: 512 blocks, 2-phase counted-vmcnt ----------------
// job = bid>>8; rem = bid&255; s = rem>>1 (8 gate cells x 4 segs = 32 packed cols);
// r0 = (rem&1)*64. GEMM M=64, N=32, K=1024, BK=128 double-buffered.
// Pipeline per chunk: STAGE(next,buf^1) -> vmcnt(6) -> s_barrier -> compute(buf) -> s_barrier.
// Loads stay in flight across barriers (T4); LDS 48 KB -> 2 blocks/CU unchanged.
__global__ __launch_bounds__(256) void k_step(
    const u16* __restrict__ WgHp, const u16* __restrict__ rWgHp,
    const u16* __restrict__ pre_t,           // [BC][8192] bf16; job*4096 col offset
    const float* __restrict__ nbrv,
    u16* __restrict__ Hb2, u16* __restrict__ rHb2,
    float* __restrict__ Cs, float* __restrict__ rCs,
    float* __restrict__ Hf, float* __restrict__ rHf,
    int ph, int last)
{
  __shared__ u16 ldsA[2][64*128];   // 32 KB
  __shared__ u16 ldsB[2][32*128];   // 16 KB

  const int tid  = threadIdx.x;
  const int lane = tid & 63;
  const int w    = tid >> 6;          // 0..3
  const int bid  = blockIdx.x;
  const int job  = bid >> 8;
  const int rem  = bid & 255;
  const int s    = rem >> 1;
  const int r0   = (rem & 1) * 64;

  const u16* Bp   = (job ? rWgHp : WgHp) + (size_t)s*32*1024;
  const u16* Ab   = (job ? rHb2 : Hb2) + (size_t)ph*BC*NN + (size_t)r0*NN;
  const u16* pret = pre_t + (size_t)job*4096;
  u16* Hnext  = (job ? rHb2 : Hb2) + (size_t)(ph^1)*BC*NN;
  float* Csb  = job ? rCs : Cs;
  float* Hfin = job ? rHf : Hf;

  const int r4  = lane >> 4;           // 0..3 row offset within 1KB issue
  const int g16 = lane & 15;           // 16B group within 256B row

  // 6 GLD16 per wave per chunk: 4 for A (16 rows), 2 for B (8 rows)
  auto STAGE = [&](int ck, int buf){
    int k0 = ck*128;
    #pragma unroll
    for (int c = 0; c < 4; ++c){
      int rowb = w*16 + c*4;
      int row = rowb + r4;
      int srcg = (g16 & 8) | ((g16 & 7) ^ (row & 7));
      GLD16(Ab + (size_t)row*1024 + k0 + srcg*8, &ldsA[buf][rowb*128]);
    }
    #pragma unroll
    for (int c = 0; c < 2; ++c){
      int rowb = w*8 + c*4;
      int row = rowb + r4;
      int srcg = (g16 & 8) | ((g16 & 7) ^ (row & 7));
      GLD16(Bp + (size_t)row*1024 + k0 + srcg*8, &ldsB[buf][rowb*128]);
    }
  };

  f32x4 acc[2] = {};
  STAGE(0, 0);
  #pragma unroll
  for (int t = 0; t < 8; ++t){
    const int cur = t & 1;
    if (t < 7){
      STAGE(t+1, cur^1);
      asm volatile("s_waitcnt vmcnt(6)" ::: "memory");   // cur's 6 oldest done; next's stay in flight
    } else {
      asm volatile("s_waitcnt vmcnt(0)" ::: "memory");
    }
    __builtin_amdgcn_sched_barrier(0);
    __builtin_amdgcn_s_barrier();
    #pragma unroll
    for (int kk = 0; kk < 4; ++kk){
      int idx = kk*4 + (lane >> 4);
      int rowa = w*16 + (lane & 15);
      int pa = (idx & 8) | ((idx & 7) ^ (rowa & 7));
      bf16x8 af = *(const bf16x8*)&ldsA[cur][rowa*128 + pa*8];
      #pragma unroll
      for (int ni = 0; ni < 2; ++ni){
        int rowb2 = ni*16 + (lane & 15);
        int pb = (idx & 8) | ((idx & 7) ^ (rowb2 & 7));
        bf16x8 bv = *(const bf16x8*)&ldsB[cur][rowb2*128 + pb*8];
        acc[ni] = __builtin_amdgcn_mfma_f32_16x16x32_bf16(af, bv, acc[ni], 0, 0, 0);
      }
    }
    __builtin_amdgcn_sched_barrier(0);
    __builtin_amdgcn_s_barrier();   // protect buf[cur] before chunk t+1 stages into it
  }

  // epilogue: + pre, gates via shfl_xor(8) (round-4/8/9 verified mapping)
  #pragma unroll
  for (int ni = 0; ni < 2; ++ni){
    int pcol = ni*16 + (lane & 15);
    int gcol = (pcol >> 3)*1024 + s*8 + (pcol & 7);
    #pragma unroll
    for (int q = 0; q < 4; ++q){
      int row = r0 + w*16 + (lane >> 4)*4 + q;
      acc[ni][q] += b2f(pret[(size_t)row*8192 + gcol]);
    }
  }
  const bool act = (lane & 15) < 8;
  const int  c   = lane & 7;
  const int  col = s*8 + c;
  float fac = 1.f;
  if (!job && act) fac = nbrv[col];
  #pragma unroll
  for (int q = 0; q < 4; ++q){
    float a0 = acc[0][q], a1 = acc[1][q];
    float p1 = __shfl_xor(a0, 8);   // seg1 (i-gate)
    float p3 = __shfl_xor(a1, 8);   // seg3 (Ct)
    if (act){
      int row = r0 + w*16 + (lane >> 4)*4 + q;
      float fg = sigf(a0), ig = sigf(p1), og = sigf(a1), ct = tanhf(p3);
      size_t cidx = (size_t)row*NN + col;
      float cs = fg*Csb[cidx]*fac + ig*ct;
      Csb[cidx] = cs;
      float h = og*tanhf(cs);
      Hnext[cidx] = f2b(h);
      if (last) Hfin[cidx] = h;
    }
  }
}

// ---------------- last-step statistics ----------------
__global__ void k_var1(const u16* __restrict__ Xl, const u16* __restrict__ gcl,
                       float* __restrict__ part){
  int ch = blockIdx.x & 1, seg = blockIdx.x >> 1;   // 64 blocks
  int tid = threadIdx.x;
  float s1=0.f,q1=0.f,s2=0.f,q2=0.f;
  for (int bb = 0; bb < 2; ++bb){
    int row = (seg*2+bb)*2 + ch;
    const u16* xr = Xl + (size_t)row*1024;
    for (int n = tid; n < 1024; n += 256){ float v = b2f(xr[n]); s1 += v; q1 += v*v; }
    const u16* gr = gcl + (size_t)row*3072;
    for (int n = tid; n < 3072; n += 256){ float v = b2f(gr[n]); s2 += v; q2 += v*v; }
  }
  __shared__ float red[256][4];
  red[tid][0]=s1; red[tid][1]=q1; red[tid][2]=s2; red[tid][3]=q2;
  __syncthreads();
  for (int st = 128; st > 0; st >>= 1){
    if (tid < st){ for (int z = 0; z < 4; ++z) red[tid][z] += red[tid+st][z]; }
    __syncthreads();
  }
  if (tid == 0){ for (int z = 0; z < 4; ++z) part[(size_t)blockIdx.x*4 + z] = red[0][z]; }
}

// fused var2 + pred + conv: one thread per (b,n), 256 blocks
__global__ void k_out(const float* __restrict__ H, const float* __restrict__ rH,
                      const float* __restrict__ part, const float* __restrict__ cptr,
                      const float* __restrict__ cw, const float* __restrict__ cb,
                      float* __restrict__ out){
  __shared__ float vsh[4];
  int tid = threadIdx.x;
  if (tid < 4){
    int ch = tid & 1, which = tid >> 1;   // which: 0=var1, 1=var2
    float s = 0.f, q = 0.f;
    for (int seg = 0; seg < 32; ++seg){
      const float* p = part + (size_t)(seg*2+ch)*4 + which*2;
      s += p[0]; q += p[1];
    }
    float n = which ? 196608.f : 65536.f;
    vsh[tid] = (q - s*s/n) / (n - 1.f);
  }
  __syncthreads();
  int idx = blockIdx.x*256 + tid;   // 64*1024
  int n = idx & 1023, b = idx >> 10;
  float c0 = cptr[0];
  float v10 = vsh[0], v11 = vsh[1], v20 = vsh[2], v21 = vsh[3];
  size_t i0 = (size_t)(b*2+0)*1024 + n, i1 = (size_t)(b*2+1)*1024 + n;
  float p0 = (H[i0]*v10*c0 + rH[i0]*v20) / (v10 + v20*c0);
  float p1 = (H[i1]*v11*c0 + rH[i1]*v21) / (v11 + v21*c0);
  float* ob = out + (size_t)b*24*1024 + n;
  #pragma unroll
  for (int o = 0; o < 24; ++o)
    ob[(size_t)o*1024] = p0*cw[o*2+0] + p1*cw[o*2+1] + cb[o];
}

// ---------------- launch ----------------
extern "C" void kernel_launch(void* const* d_in, const int* in_sizes, int n_in,
                              void* d_out, int out_size, void* d_ws, size_t ws_size,
                              hipStream_t stream) {
  const float* inputs = (const float*)d_in[0];
  const float* adj    = (const float*)d_in[1];
  const float* gcw    = (const float*)d_in[2];
  const float* Wf  = (const float*)d_in[3];  const float* bf_ = (const float*)d_in[4];
  const float* Wi  = (const float*)d_in[5];  const float* bi_ = (const float*)d_in[6];
  const float* Wo  = (const float*)d_in[7];  const float* bo_ = (const float*)d_in[8];
  const float* Wc  = (const float*)d_in[9];  const float* bc_ = (const float*)d_in[10];
  const float* rWf = (const float*)d_in[11]; const float* rbf = (const float*)d_in[12];
  const float* rWi = (const float*)d_in[13]; const float* rbi = (const float*)d_in[14];
  const float* rWo = (const float*)d_in[15]; const float* rbo = (const float*)d_in[16];
  const float* rWc = (const float*)d_in[17]; const float* rbc = (const float*)d_in[18];
  const float* nw     = (const float*)d_in[19];
  const float* cscal  = (const float*)d_in[20];
  const float* convw  = (const float*)d_in[21];
  const float* convb  = (const float*)d_in[22];
  float* out = (float*)d_out;

  char* cur = (char*)d_ws;
  auto alloc = [&](size_t bytes) -> void* {
    void* p = cur; cur += (bytes + 255) & ~(size_t)255; return p;
  };
  u16*   Xb     = (u16*)  alloc((size_t)LS*BC*NN*2);      // 6 MB
  float* csum   = (float*)alloc((size_t)64*1024*4);
  float* tmpv   = (float*)alloc(1024*4);
  u16*   anormT = (u16*)  alloc((size_t)NN*NN*2);         // 2 MB
  u16*   Apowb  = (u16*)  alloc((size_t)3*NN*NN*2);       // 6 MB
  float* nbrv   = (float*)alloc(1024*4);
  u16*   effb   = (u16*)  alloc((size_t)3*NN*NN*2);       // 6 MB
  u16*   effbT  = (u16*)  alloc((size_t)3*NN*NN*2);       // 6 MB
  u16*   Wgxb   = (u16*)  alloc((size_t)4096*3072*2);     // 24 MB
  u16*   WgHp   = (u16*)  alloc((size_t)4096*1024*2);     // 8 MB
  u16*   rWgHp  = (u16*)  alloc((size_t)4096*1024*2);     // 8 MB
  u16*   Bcat   = (u16*)  alloc((size_t)8192*1024*2);     // 16 MB: [Cw; rWgx]
  float* bgcat  = (float*)alloc(8192*4);
  u16*   gclb   = (u16*)  alloc((size_t)BC*3072*2);
  u16*   prebuf = (u16*)  alloc((size_t)3072*8192*2);     // 48 MB bf16
  char*  zbase  = cur;
  u16*   Hb2    = (u16*)  alloc((size_t)2*BC*NN*2);
  u16*   rHb2   = (u16*)  alloc((size_t)2*BC*NN*2);
  float* Cs     = (float*)alloc((size_t)BC*NN*4);
  float* rCs    = (float*)alloc((size_t)BC*NN*4);
  size_t zlen   = (size_t)(cur - zbase);
  float* Hfv    = (float*)alloc((size_t)BC*NN*4);
  float* rHfv   = (float*)alloc((size_t)BC*NN*4);
  float* part   = (float*)alloc(64*4*4);

  u16* A1b = Apowb;
  u16* A2b = Apowb + (size_t)NN*NN;
  u16* A3b = Apowb + (size_t)2*NN*NN;
  u16* Cwb   = Bcat;                       // rows 0..4095
  u16* rWgxb = Bcat + (size_t)4096*1024;   // rows 4096..8191

  // fused preprocessing: transpose + colsum1 + packbias + pack (8 elems/thread)
  k_prep<<<592 + (2097152+1048576)/256, 256, 0, stream>>>(
      inputs, adj, Wf, Wi, Wo, Wc, rWf, rWi, rWo, rWc,
      bf_, bi_, bo_, bc_, rbf, rbi, rbo, rbc,
      Xb, csum, Wgxb, WgHp, rWgxb, rWgHp, bgcat);
  k_colsum2<<<4, 256, 0, stream>>>(csum, tmpv);
  dim3 g16(16, 16);
  k_anormT<<<g16, 256, 0, stream>>>(adj, tmpv, A1b, anormT);
  // adjacency powers, 64^2 tiles BK=128
  k_mfma64<<<g16, 256, 0, stream>>>(A1b, anormT, 1024, 1, 0, A2b, 1024);
  k_mfma64<<<g16, 256, 0, stream>>>(A2b, anormT, 1024, 1, 0, A3b, 1024);
  k_nbr<<<NN, 256, 0, stream>>>(A3b, nw, nbrv);
  dim3 geff(16, 48);
  k_effT<<<geff, 256, 0, stream>>>(Apowb, gcw, effb, effbT);

  // Cw = Wgx @ eff (4096x1024, K=3072), XCD-swizzled (grid (16,64))
  dim3 gcwg(16, 64);
  k_mfma64<<<gcwg, 256, 0, stream>>>(Wgxb, effbT, 3072, 0, 1, Cwb, 1024);
  // pre = X @ [Cw; rWgx]^T + biascat (3072x8192, K=1024), XCD-swizzled
  dim3 gpre(64, 24);
  k_mfma_pre<<<gpre, 256, 0, stream>>>(Xb, Bcat, bgcat, prebuf);
  // last-step gc (for var only)
  dim3 ggcl(48, 2);
  k_mfma64<<<ggcl, 256, 0, stream>>>(Xb + (size_t)(LS-1)*BC*NN, effb, 1024, 0, 0, gclb, 3072);

  hipMemsetAsync(zbase, 0, zlen, stream);

  // 24 fused steps
  for (int t = 0; t < LS; ++t)
    k_step<<<512, 256, 0, stream>>>(WgHp, rWgHp,
        prebuf + (size_t)t*BC*8192,
        nbrv, Hb2, rHb2, Cs, rCs, Hfv, rHfv, t & 1, t == LS-1);

  k_var1<<<64, 256, 0, stream>>>(Xb + (size_t)(LS-1)*BC*NN, gclb, part);
  k_out<<<(64*1024)/256, 256, 0, stream>>>(Hfv, rHfv, part, cscal, convw, convb, out);
}